// Round 7
// baseline (736.032 us; speedup 1.0000x reference)
//
#include <hip/hip_runtime.h>
#include <hip/hip_bf16.h>

// Problem constants
#define BB 8
#define NN 2048
#define DD 512
#define CFF 128
#define MT (BB*NN)   // 16384

typedef _Float16 half_t;
typedef __attribute__((ext_vector_type(8))) _Float16 half8;
typedef __attribute__((ext_vector_type(4))) float floatx4;
typedef __attribute__((ext_vector_type(4))) unsigned int uint4v;

#define MFMA16(a,b,c) __builtin_amdgcn_mfma_f32_16x16x32_f16((a),(b),(c),0,0,0)

// ============================================================================
// FALLBACK: 128x128 fp16-split GEMM (r5, proven-pass). 4 waves 64x64, BK=32.
// EPI: 0 = alpha*acc -> Cf ; 1 = alpha*acc hi/lo split -> Chi/Clo
//      3 = max(alpha*acc - tvec,0) + atomic row sums ; 4 = h+thresh fuse
// ============================================================================
template<int EPI>
__global__ __launch_bounds__(256) void gemm_f16s(
    const half_t* __restrict__ Ahi, const half_t* __restrict__ Alo, long lda, long sA,
    const half_t* __restrict__ Bhi, const half_t* __restrict__ Blo, long ldb, long sB,
    float* __restrict__ Cf, half_t* __restrict__ Chi, half_t* __restrict__ Clo,
    long ldc, long sC, long slotS,
    int K, float alpha, const float* __restrict__ bias, const float* __restrict__ tvec,
    float* __restrict__ rsum)
{
    const int gx = gridDim.x, gy = gridDim.y;
    int d = blockIdx.x + gx * (blockIdx.y + gy * blockIdx.z);
    int total = gx * gy * gridDim.z;
    int t0 = (d & 7) * (total >> 3) + (d >> 3);
    int bx = t0 % gx;
    int t1 = t0 / gx;
    int by = t1 % gy;
    int bz = t1 / gy;

    const int tid = threadIdx.x;
    const int row0 = by * 128, col0 = bx * 128;
    const long z = bz;
    const half_t* pAh = Ahi + z * sA + (long)row0 * lda;
    const half_t* pAl = Alo + z * sA + (long)row0 * lda;
    const half_t* pBh = Bhi + z * sB + (long)col0 * ldb;
    const half_t* pBl = Blo + z * sB + (long)col0 * ldb;

    __shared__ half_t lds[2][4][4096];

    const int l  = tid & 63;
    const int w  = tid >> 6;
    const int wr = w >> 1, wc = w & 1;
    const int Rw = wr * 64, Cw = wc * 64;
    const int rl = l & 15, kc = l >> 4;
    const int swz = (kc ^ ((rl >> 1) & 3)) * 8;

    floatx4 acc[4][4];
#pragma unroll
    for (int m = 0; m < 4; ++m)
#pragma unroll
        for (int n = 0; n < 4; ++n) acc[m][n] = (floatx4){0.f, 0.f, 0.f, 0.f};

    const int r0s = tid >> 2,         c0s = tid & 3;
    const int r1s = (tid + 256) >> 2, c1s = tid & 3;
    const int off0 = r0s * 32 + ((c0s ^ ((r0s >> 1) & 3)) * 8);
    const int off1 = r1s * 32 + ((c1s ^ ((r1s >> 1) & 3)) * 8);

    auto load_regs = [&](int k0, uint4v* r) {
        long ga0 = (long)r0s * lda + k0 + c0s * 8;
        long gb0 = (long)r0s * ldb + k0 + c0s * 8;
        long ga1 = (long)r1s * lda + k0 + c1s * 8;
        long gb1 = (long)r1s * ldb + k0 + c1s * 8;
        r[0] = *(const uint4v*)(pAh + ga0);
        r[1] = *(const uint4v*)(pAl + ga0);
        r[2] = *(const uint4v*)(pBh + gb0);
        r[3] = *(const uint4v*)(pBl + gb0);
        r[4] = *(const uint4v*)(pAh + ga1);
        r[5] = *(const uint4v*)(pAl + ga1);
        r[6] = *(const uint4v*)(pBh + gb1);
        r[7] = *(const uint4v*)(pBl + gb1);
    };
    auto write_lds = [&](int buf, const uint4v* r) {
        *(uint4v*)&lds[buf][0][off0] = r[0];
        *(uint4v*)&lds[buf][1][off0] = r[1];
        *(uint4v*)&lds[buf][2][off0] = r[2];
        *(uint4v*)&lds[buf][3][off0] = r[3];
        *(uint4v*)&lds[buf][0][off1] = r[4];
        *(uint4v*)&lds[buf][1][off1] = r[5];
        *(uint4v*)&lds[buf][2][off1] = r[6];
        *(uint4v*)&lds[buf][3][off1] = r[7];
    };

    const int nk = K >> 5;
    uint4v rg[8];
    load_regs(0, rg);
    write_lds(0, rg);
#pragma unroll 2
    for (int t = 0; t < nk; ++t) {
        __syncthreads();
        if (t + 1 < nk) load_regs((t + 1) << 5, rg);
        const int cur = t & 1;
        const half_t* bAh = &lds[cur][0][0];
        const half_t* bAl = &lds[cur][1][0];
        const half_t* bBh = &lds[cur][2][0];
        const half_t* bBl = &lds[cur][3][0];
        half8 af[4][2], bf[4][2];
#pragma unroll
        for (int m = 0; m < 4; ++m) {
            int off = (Rw + m * 16 + rl) * 32 + swz;
            af[m][0] = *(const half8*)(bAh + off);
            af[m][1] = *(const half8*)(bAl + off);
        }
#pragma unroll
        for (int n = 0; n < 4; ++n) {
            int off = (Cw + n * 16 + rl) * 32 + swz;
            bf[n][0] = *(const half8*)(bBh + off);
            bf[n][1] = *(const half8*)(bBl + off);
        }
        __builtin_amdgcn_s_setprio(1);
#pragma unroll
        for (int m = 0; m < 4; ++m)
#pragma unroll
            for (int n = 0; n < 4; ++n) {
                acc[m][n] = MFMA16(af[m][0], bf[n][0], acc[m][n]);
                acc[m][n] = MFMA16(af[m][1], bf[n][0], acc[m][n]);
                acc[m][n] = MFMA16(af[m][0], bf[n][1], acc[m][n]);
            }
        __builtin_amdgcn_s_setprio(0);
        if (t + 1 < nk) write_lds((t + 1) & 1, rg);
    }

    if (EPI == 0) {
#pragma unroll
        for (int m = 0; m < 4; ++m)
#pragma unroll
            for (int n = 0; n < 4; ++n) {
                int col = col0 + Cw + n * 16 + rl;
#pragma unroll
                for (int r = 0; r < 4; ++r) {
                    int row = row0 + Rw + m * 16 + kc * 4 + r;
                    Cf[z * sC + (long)row * ldc + col] = acc[m][n][r] * alpha;
                }
            }
    } else if (EPI == 1) {
#pragma unroll
        for (int m = 0; m < 4; ++m)
#pragma unroll
            for (int n = 0; n < 4; ++n) {
                int col = col0 + Cw + n * 16 + rl;
                long obase = (long)(col >> 9) * slotS + z * sC + (col & 511);
#pragma unroll
                for (int r = 0; r < 4; ++r) {
                    int row = row0 + Rw + m * 16 + kc * 4 + r;
                    long o = obase + (long)row * ldc;
                    float v = acc[m][n][r] * alpha;
                    half_t hh = (half_t)v;
                    Chi[o] = hh;
                    Clo[o] = (half_t)(v - (float)hh);
                }
            }
    } else if (EPI == 3) {
        const float* tv = tvec + z * NN;
        float* rs = rsum + z * NN;
#pragma unroll
        for (int m = 0; m < 4; ++m) {
#pragma unroll
            for (int r = 0; r < 4; ++r) {
                int row = row0 + Rw + m * 16 + kc * 4 + r;
                float tvr = tv[row];
                float partial = 0.f;
#pragma unroll
                for (int n = 0; n < 4; ++n) {
                    int col = col0 + Cw + n * 16 + rl;
                    float v = fmaxf(acc[m][n][r] * alpha - tvr, 0.f);
                    Cf[z * sC + (long)row * ldc + col] = v;
                    partial += v;
                }
                partial += __shfl_xor(partial, 1);
                partial += __shfl_xor(partial, 2);
                partial += __shfl_xor(partial, 4);
                partial += __shfl_xor(partial, 8);
                if (rl == 0) atomicAdd(&rs[row], partial);
            }
        }
    } else {  // EPI == 4: fused h + thresh
        float w2v[4], bv[4];
#pragma unroll
        for (int n = 0; n < 4; ++n) {
            int col = Cw + n * 16 + rl;
            bv[n]  = bias[col];
            w2v[n] = tvec[col];
        }
#pragma unroll
        for (int m = 0; m < 4; ++m) {
#pragma unroll
            for (int r = 0; r < 4; ++r) {
                int row = row0 + Rw + m * 16 + kc * 4 + r;
                float partial = 0.f;
#pragma unroll
                for (int n = 0; n < 4; ++n) {
                    float v = acc[m][n][r] + bv[n];
                    v = (v >= 0.f) ? v : 0.1f * v;
                    partial += v * w2v[n];
                }
                partial += __shfl_xor(partial, 1);
                partial += __shfl_xor(partial, 2);
                partial += __shfl_xor(partial, 4);
                partial += __shfl_xor(partial, 8);
                if (rl == 0) atomicAdd(&rsum[row], partial);
            }
        }
    }
}

// ============================================================================
// BIG PATH: BMx256 fp16-split GEMM, 8 waves (2x4), wave tile (BM/2)x64, BK=32.
// Dynamic LDS (2*PERBUF halves). Staging FIX vs r6 (rule #21): global offset
// uses LOGICAL chunk (s&3); LDS offset uses SWIZZLED position (g ^ f(row)).
// Read side applies the same XOR -> retrieves the correct k-chunk.
// ============================================================================
template<int MF, int EPI>
__global__ __launch_bounds__(512, 2) void gemm256(
    const half_t* __restrict__ Ahi, const half_t* __restrict__ Alo, long lda, long sA,
    const half_t* __restrict__ Bhi, const half_t* __restrict__ Blo, long ldb, long sB,
    float* __restrict__ Cf, half_t* __restrict__ Chi, half_t* __restrict__ Clo,
    long ldc, long sC, long slotS,
    int K, float alpha, const float* __restrict__ tvec, float* __restrict__ rsum)
{
    constexpr int BM    = MF * 32;
    constexpr int ATILE = BM * 32;
    constexpr int BTILE = 256 * 32;
    constexpr int PERBUF = 2 * ATILE + 2 * BTILE;
    constexpr int oAh = 0, oAl = ATILE, oBh = 2 * ATILE, oBl = 2 * ATILE + BTILE;
    constexpr int RA = (MF == 8) ? 2 : 1;

    extern __shared__ half_t lds[];     // 2*PERBUF halves, passed at launch

    const int gx = gridDim.x, gy = gridDim.y;
    int d = blockIdx.x + gx * (blockIdx.y + gy * blockIdx.z);
    int total = gx * gy * gridDim.z;
    int t0 = (d & 7) * (total >> 3) + (d >> 3);
    int bx = t0 % gx;
    int t1 = t0 / gx;
    int by = t1 % gy;
    int bz = t1 / gy;

    const int tid = threadIdx.x;
    const int row0 = by * BM, col0 = bx * 256;
    const long z = bz;
    const half_t* pAh = Ahi + z * sA + (long)row0 * lda;
    const half_t* pAl = Alo + z * sA + (long)row0 * lda;
    const half_t* pBh = Bhi + z * sB + (long)col0 * ldb;
    const half_t* pBl = Blo + z * sB + (long)col0 * ldb;

    const int l  = tid & 63;
    const int w  = tid >> 6;
    const int wr = w >> 2, wc = w & 3;
    const int Rw = wr * (BM / 2), Cw = wc * 64;
    const int rl = l & 15, kc = l >> 4;
    const int swz = (kc ^ ((rl >> 1) & 3)) * 8;

    floatx4 acc[MF][4];
#pragma unroll
    for (int m = 0; m < MF; ++m)
#pragma unroll
        for (int n = 0; n < 4; ++n) acc[m][n] = (floatx4){0.f, 0.f, 0.f, 0.f};

    // staging: s = tid + u*512 -> row = s>>2, LOGICAL chunk g = s&3,
    // LDS position p = g ^ ((row>>1)&3)   [THE r6 BUG FIX]
    long goffA[RA]; int loffA[RA];
    long goffB[2];  int loffB[2];
#pragma unroll
    for (int u = 0; u < RA; ++u) {
        int s = tid + u * 512; int r = s >> 2; int g = s & 3; int p = g ^ ((r >> 1) & 3);
        goffA[u] = (long)r * lda + g * 8; loffA[u] = r * 32 + p * 8;
    }
#pragma unroll
    for (int u = 0; u < 2; ++u) {
        int s = tid + u * 512; int r = s >> 2; int g = s & 3; int p = g ^ ((r >> 1) & 3);
        goffB[u] = (long)r * ldb + g * 8; loffB[u] = r * 32 + p * 8;
    }

    uint4v rgA[RA][2], rgB[2][2];
    auto load_regs = [&](int k0) {
#pragma unroll
        for (int u = 0; u < RA; ++u) {
            rgA[u][0] = *(const uint4v*)(pAh + goffA[u] + k0);
            rgA[u][1] = *(const uint4v*)(pAl + goffA[u] + k0);
        }
#pragma unroll
        for (int u = 0; u < 2; ++u) {
            rgB[u][0] = *(const uint4v*)(pBh + goffB[u] + k0);
            rgB[u][1] = *(const uint4v*)(pBl + goffB[u] + k0);
        }
    };
    auto write_lds = [&](int buf) {
        half_t* bp = lds + buf * PERBUF;
#pragma unroll
        for (int u = 0; u < RA; ++u) {
            *(uint4v*)&bp[oAh + loffA[u]] = rgA[u][0];
            *(uint4v*)&bp[oAl + loffA[u]] = rgA[u][1];
        }
#pragma unroll
        for (int u = 0; u < 2; ++u) {
            *(uint4v*)&bp[oBh + loffB[u]] = rgB[u][0];
            *(uint4v*)&bp[oBl + loffB[u]] = rgB[u][1];
        }
    };

    const int nk = K >> 5;
    load_regs(0);
    write_lds(0);
#pragma unroll 2
    for (int t = 0; t < nk; ++t) {
        __syncthreads();
        if (t + 1 < nk) load_regs((t + 1) << 5);
        const half_t* bp = lds + (t & 1) * PERBUF;
        half8 bf[4][2];
#pragma unroll
        for (int n = 0; n < 4; ++n) {
            int off = (Cw + n * 16 + rl) * 32 + swz;
            bf[n][0] = *(const half8*)(bp + oBh + off);
            bf[n][1] = *(const half8*)(bp + oBl + off);
        }
#pragma unroll
        for (int mp = 0; mp < MF / 2; ++mp) {
            half8 af[2][2];
#pragma unroll
            for (int i = 0; i < 2; ++i) {
                int off = (Rw + (mp * 2 + i) * 16 + rl) * 32 + swz;
                af[i][0] = *(const half8*)(bp + oAh + off);
                af[i][1] = *(const half8*)(bp + oAl + off);
            }
            __builtin_amdgcn_s_setprio(1);
#pragma unroll
            for (int i = 0; i < 2; ++i)
#pragma unroll
                for (int n = 0; n < 4; ++n) {
                    const int m = mp * 2 + i;
                    acc[m][n] = MFMA16(af[i][0], bf[n][0], acc[m][n]);
                    acc[m][n] = MFMA16(af[i][1], bf[n][0], acc[m][n]);
                    acc[m][n] = MFMA16(af[i][0], bf[n][1], acc[m][n]);
                }
            __builtin_amdgcn_s_setprio(0);
        }
        if (t + 1 < nk) write_lds((t + 1) & 1);
    }

    if (EPI == 0) {
#pragma unroll
        for (int m = 0; m < MF; ++m)
#pragma unroll
            for (int n = 0; n < 4; ++n) {
                int col = col0 + Cw + n * 16 + rl;
#pragma unroll
                for (int r = 0; r < 4; ++r) {
                    int row = row0 + Rw + m * 16 + kc * 4 + r;
                    Cf[z * sC + (long)row * ldc + col] = acc[m][n][r] * alpha;
                }
            }
    } else if (EPI == 1) {
#pragma unroll
        for (int m = 0; m < MF; ++m)
#pragma unroll
            for (int n = 0; n < 4; ++n) {
                int col = col0 + Cw + n * 16 + rl;
                long obase = (long)(col >> 9) * slotS + z * sC + (col & 511);
#pragma unroll
                for (int r = 0; r < 4; ++r) {
                    int row = row0 + Rw + m * 16 + kc * 4 + r;
                    long o = obase + (long)row * ldc;
                    float v = acc[m][n][r] * alpha;
                    half_t hh = (half_t)v;
                    Chi[o] = hh;
                    Clo[o] = (half_t)(v - (float)hh);
                }
            }
    } else {  // EPI == 3
        const float* tv = tvec + z * NN;
        float* rs = rsum + z * NN;
#pragma unroll
        for (int m = 0; m < MF; ++m) {
#pragma unroll
            for (int r = 0; r < 4; ++r) {
                int row = row0 + Rw + m * 16 + kc * 4 + r;
                float tvr = tv[row];
                float partial = 0.f;
#pragma unroll
                for (int n = 0; n < 4; ++n) {
                    int col = col0 + Cw + n * 16 + rl;
                    float v = fmaxf(acc[m][n][r] * alpha - tvr, 0.f);
                    Cf[z * sC + (long)row * ldc + col] = v;
                    partial += v;
                }
                partial += __shfl_xor(partial, 1);
                partial += __shfl_xor(partial, 2);
                partial += __shfl_xor(partial, 4);
                partial += __shfl_xor(partial, 8);
                if (rl == 0) atomicAdd(&rs[row], partial);
            }
        }
    }
}

// ============================================================================
// fused h+thresh 128x128 kernel (r5-pattern staging, correct swizzle):
// thresh += leakyrelu(att@W1 + b1) @ W2
// ============================================================================
__global__ __launch_bounds__(256) void gemm_h(
    const half_t* __restrict__ Ahi, const half_t* __restrict__ Alo, long lda,
    const half_t* __restrict__ Bhi, const half_t* __restrict__ Blo, long ldb,
    int K, const float* __restrict__ bias, const float* __restrict__ tvec,
    float* __restrict__ rsum)
{
    const int gx = gridDim.x, gy = gridDim.y;
    int d = blockIdx.x + gx * blockIdx.y;
    int total = gx * gy;
    int t0 = (d & 7) * (total >> 3) + (d >> 3);
    int bx = t0 % gx;
    int by = t0 / gx;

    const int tid = threadIdx.x;
    const int row0 = by * 128, col0 = bx * 128;
    const half_t* pAh = Ahi + (long)row0 * lda;
    const half_t* pAl = Alo + (long)row0 * lda;
    const half_t* pBh = Bhi + (long)col0 * ldb;
    const half_t* pBl = Blo + (long)col0 * ldb;

    __shared__ half_t lds[2][4][4096];

    const int l  = tid & 63;
    const int w  = tid >> 6;
    const int wr = w >> 1, wc = w & 1;
    const int Rw = wr * 64, Cw = wc * 64;
    const int rl = l & 15, kc = l >> 4;
    const int swz = (kc ^ ((rl >> 1) & 3)) * 8;

    floatx4 acc[4][4];
#pragma unroll
    for (int m = 0; m < 4; ++m)
#pragma unroll
        for (int n = 0; n < 4; ++n) acc[m][n] = (floatx4){0.f, 0.f, 0.f, 0.f};

    const int r0s = tid >> 2,         c0s = tid & 3;
    const int r1s = (tid + 256) >> 2, c1s = tid & 3;
    const int off0 = r0s * 32 + ((c0s ^ ((r0s >> 1) & 3)) * 8);
    const int off1 = r1s * 32 + ((c1s ^ ((r1s >> 1) & 3)) * 8);

    auto load_regs = [&](int k0, uint4v* r) {
        long ga0 = (long)r0s * lda + k0 + c0s * 8;
        long gb0 = (long)r0s * ldb + k0 + c0s * 8;
        long ga1 = (long)r1s * lda + k0 + c1s * 8;
        long gb1 = (long)r1s * ldb + k0 + c1s * 8;
        r[0] = *(const uint4v*)(pAh + ga0);
        r[1] = *(const uint4v*)(pAl + ga0);
        r[2] = *(const uint4v*)(pBh + gb0);
        r[3] = *(const uint4v*)(pBl + gb0);
        r[4] = *(const uint4v*)(pAh + ga1);
        r[5] = *(const uint4v*)(pAl + ga1);
        r[6] = *(const uint4v*)(pBh + gb1);
        r[7] = *(const uint4v*)(pBl + gb1);
    };
    auto write_lds = [&](int buf, const uint4v* r) {
        *(uint4v*)&lds[buf][0][off0] = r[0];
        *(uint4v*)&lds[buf][1][off0] = r[1];
        *(uint4v*)&lds[buf][2][off0] = r[2];
        *(uint4v*)&lds[buf][3][off0] = r[3];
        *(uint4v*)&lds[buf][0][off1] = r[4];
        *(uint4v*)&lds[buf][1][off1] = r[5];
        *(uint4v*)&lds[buf][2][off1] = r[6];
        *(uint4v*)&lds[buf][3][off1] = r[7];
    };

    const int nk = K >> 5;
    uint4v rg[8];
    load_regs(0, rg);
    write_lds(0, rg);
#pragma unroll 2
    for (int t = 0; t < nk; ++t) {
        __syncthreads();
        if (t + 1 < nk) load_regs((t + 1) << 5, rg);
        const int cur = t & 1;
        const half_t* bAh = &lds[cur][0][0];
        const half_t* bAl = &lds[cur][1][0];
        const half_t* bBh = &lds[cur][2][0];
        const half_t* bBl = &lds[cur][3][0];
        half8 af[4][2], bf[4][2];
#pragma unroll
        for (int m = 0; m < 4; ++m) {
            int off = (Rw + m * 16 + rl) * 32 + swz;
            af[m][0] = *(const half8*)(bAh + off);
            af[m][1] = *(const half8*)(bAl + off);
        }
#pragma unroll
        for (int n = 0; n < 4; ++n) {
            int off = (Cw + n * 16 + rl) * 32 + swz;
            bf[n][0] = *(const half8*)(bBh + off);
            bf[n][1] = *(const half8*)(bBl + off);
        }
        __builtin_amdgcn_s_setprio(1);
#pragma unroll
        for (int m = 0; m < 4; ++m)
#pragma unroll
            for (int n = 0; n < 4; ++n) {
                acc[m][n] = MFMA16(af[m][0], bf[n][0], acc[m][n]);
                acc[m][n] = MFMA16(af[m][1], bf[n][0], acc[m][n]);
                acc[m][n] = MFMA16(af[m][0], bf[n][1], acc[m][n]);
            }
        __builtin_amdgcn_s_setprio(0);
        if (t + 1 < nk) write_lds((t + 1) & 1, rg);
    }

    float w2v[4], bv[4];
#pragma unroll
    for (int n = 0; n < 4; ++n) {
        int col = Cw + n * 16 + rl;
        bv[n]  = bias[col];
        w2v[n] = tvec[col];
    }
#pragma unroll
    for (int m = 0; m < 4; ++m) {
#pragma unroll
        for (int r = 0; r < 4; ++r) {
            int row = row0 + Rw + m * 16 + kc * 4 + r;
            float partial = 0.f;
#pragma unroll
            for (int n = 0; n < 4; ++n) {
                float v = acc[m][n][r] + bv[n];
                v = (v >= 0.f) ? v : 0.1f * v;
                partial += v * w2v[n];
            }
            partial += __shfl_xor(partial, 1);
            partial += __shfl_xor(partial, 2);
            partial += __shfl_xor(partial, 4);
            partial += __shfl_xor(partial, 8);
            if (rl == 0) atomicAdd(&rsum[row], partial);
        }
    }
}

// ============================================================================
// small f32 weight-product GEMMs: 512x512x512 x3 in one launch.
// ============================================================================
__global__ __launch_bounds__(256) void wgemm3(
    const float* __restrict__ Wq1, const float* __restrict__ Wk1,
    const float* __restrict__ Wv1, const float* __restrict__ Wo1,
    const float* __restrict__ Wq2, const float* __restrict__ Wk2,
    float* __restrict__ T0, float* __restrict__ T1, float* __restrict__ T2)
{
    const int op = blockIdx.z;
    const float* A = (op == 0) ? Wq1 : (op == 1) ? Wv1 : Wq2;
    const float* B = (op == 0) ? Wk1 : (op == 1) ? Wo1 : Wk2;
    float* C = (op == 0) ? T0 : (op == 1) ? T1 : T2;
    const bool bt = (op != 1);

    __shared__ float As[32][65];
    __shared__ float Bs[32][65];
    const int tid = threadIdx.x;
    const int i0 = blockIdx.y * 64, j0 = blockIdx.x * 64;
    const int tx = tid & 15, ty = tid >> 4;
    float acc[4][4];
#pragma unroll
    for (int i = 0; i < 4; ++i)
#pragma unroll
        for (int j = 0; j < 4; ++j) acc[i][j] = 0.f;

    for (int k0 = 0; k0 < 512; k0 += 32) {
#pragma unroll
        for (int u = 0; u < 2; ++u) {
            int e = tid + u * 256;
            int r = e >> 3, c = (e & 7) * 4;
            float4 v = *(const float4*)(A + (long)(i0 + r) * 512 + k0 + c);
            As[c][r] = v.x; As[c + 1][r] = v.y; As[c + 2][r] = v.z; As[c + 3][r] = v.w;
        }
        if (bt) {
#pragma unroll
            for (int u = 0; u < 2; ++u) {
                int e = tid + u * 256;
                int r = e >> 3, c = (e & 7) * 4;
                float4 v = *(const float4*)(B + (long)(j0 + r) * 512 + k0 + c);
                Bs[c][r] = v.x; Bs[c + 1][r] = v.y; Bs[c + 2][r] = v.z; Bs[c + 3][r] = v.w;
            }
        } else {
#pragma unroll
            for (int u = 0; u < 2; ++u) {
                int e = tid + u * 256;
                int k = e >> 4, j = (e & 15) * 4;
                *(float4*)&Bs[k][j] = *(const float4*)(B + (long)(k0 + k) * 512 + j0 + j);
            }
        }
        __syncthreads();
#pragma unroll
        for (int kk = 0; kk < 32; ++kk) {
            float av[4], bv[4];
#pragma unroll
            for (int i = 0; i < 4; ++i) av[i] = As[kk][ty * 4 + i];
#pragma unroll
            for (int j = 0; j < 4; ++j) bv[j] = Bs[kk][tx * 4 + j];
#pragma unroll
            for (int i = 0; i < 4; ++i)
#pragma unroll
                for (int j = 0; j < 4; ++j)
                    acc[i][j] = fmaf(av[i], bv[j], acc[i][j]);
        }
        __syncthreads();
    }
#pragma unroll
    for (int i = 0; i < 4; ++i)
#pragma unroll
        for (int j = 0; j < 4; ++j)
            C[(long)(i0 + ty * 4 + i) * 512 + j0 + tx * 4 + j] = acc[i][j];
}

// ============================================================================
// helpers
// ============================================================================
__device__ __forceinline__ float waveReduceMax(float v) {
#pragma unroll
    for (int o = 32; o; o >>= 1) v = fmaxf(v, __shfl_down(v, o));
    return v;
}
__device__ __forceinline__ float waveReduceSum(float v) {
#pragma unroll
    for (int o = 32; o; o >>= 1) v += __shfl_down(v, o);
    return v;
}

__global__ __launch_bounds__(256) void softmax_split_kernel(float* __restrict__ S)
{
    __shared__ float red[4];
    __shared__ float fin;
    long row = blockIdx.x;
    float* p = S + row * (long)NN;
    half_t* ph = (half_t*)p;
    half_t* pl = ph + NN;
    int t = threadIdx.x;

    float4 v0 = *reinterpret_cast<float4*>(p + t * 8);
    float4 v1 = *reinterpret_cast<float4*>(p + t * 8 + 4);

    float m = fmaxf(fmaxf(fmaxf(v0.x, v0.y), fmaxf(v0.z, v0.w)),
                    fmaxf(fmaxf(v1.x, v1.y), fmaxf(v1.z, v1.w)));
    m = waveReduceMax(m);
    if ((t & 63) == 0) red[t >> 6] = m;
    __syncthreads();
    if (t == 0) fin = fmaxf(fmaxf(red[0], red[1]), fmaxf(red[2], red[3]));
    __syncthreads();
    m = fin;

    float e[8];
    e[0] = __expf(v0.x - m); e[1] = __expf(v0.y - m); e[2] = __expf(v0.z - m); e[3] = __expf(v0.w - m);
    e[4] = __expf(v1.x - m); e[5] = __expf(v1.y - m); e[6] = __expf(v1.z - m); e[7] = __expf(v1.w - m);
    float s = ((e[0] + e[1]) + (e[2] + e[3])) + ((e[4] + e[5]) + (e[6] + e[7]));
    s = waveReduceSum(s);
    __syncthreads();
    if ((t & 63) == 0) red[t >> 6] = s;
    __syncthreads();
    if (t == 0) fin = (red[0] + red[1]) + (red[2] + red[3]);
    __syncthreads();
    float inv = 1.0f / fin;

    __syncthreads();
    half8 hv, lv;
#pragma unroll
    for (int j = 0; j < 8; ++j) {
        float pv = e[j] * inv;
        half_t hh = (half_t)pv;
        hv[j] = hh;
        lv[j] = (half_t)(pv - (float)hh);
    }
    *(half8*)(ph + t * 8) = hv;
    *(half8*)(pl + t * 8) = lv;
}

__global__ __launch_bounds__(256) void norm_kernel(float* __restrict__ S, const float* __restrict__ sums)
{
    long i = (long)blockIdx.x * 256 + threadIdx.x;
    long base = i * 8;
    long row = base >> 11;
    float inv = 1.0f / (sums[row] + 1e-9f);
    float4 v0 = *reinterpret_cast<float4*>(S + base);
    float4 v1 = *reinterpret_cast<float4*>(S + base + 4);
    v0.x = fminf(v0.x * inv, 1.0f); v0.y = fminf(v0.y * inv, 1.0f);
    v0.z = fminf(v0.z * inv, 1.0f); v0.w = fminf(v0.w * inv, 1.0f);
    v1.x = fminf(v1.x * inv, 1.0f); v1.y = fminf(v1.y * inv, 1.0f);
    v1.z = fminf(v1.z * inv, 1.0f); v1.w = fminf(v1.w * inv, 1.0f);
    *reinterpret_cast<float4*>(S + base) = v0;
    *reinterpret_cast<float4*>(S + base + 4) = v1;
}

__global__ __launch_bounds__(256) void init_aux(float* __restrict__ thresh, float* __restrict__ sums,
                                                const float* __restrict__ b2)
{
    int i = blockIdx.x * 256 + threadIdx.x;
    if (i < MT) { thresh[i] = b2[0]; sums[i] = 0.f; }
}

__global__ __launch_bounds__(256) void wprep(const float* __restrict__ W,
                                             half_t* __restrict__ Th, half_t* __restrict__ Tl,
                                             int K, int N, float mul)
{
    __shared__ float tw[32][33];
    int n0 = blockIdx.x * 32, k0 = blockIdx.y * 32;
    int c = threadIdx.x & 31, r8 = threadIdx.x >> 5;
#pragma unroll
    for (int i = 0; i < 4; ++i) {
        int r = r8 + i * 8;
        tw[r][c] = W[(long)(k0 + r) * N + n0 + c];
    }
    __syncthreads();
#pragma unroll
    for (int i = 0; i < 4; ++i) {
        int nr = r8 + i * 8;
        float v = tw[c][nr] * mul;
        half_t hh = (half_t)v;
        Th[(long)(n0 + nr) * K + k0 + c] = hh;
        Tl[(long)(n0 + nr) * K + k0 + c] = (half_t)(v - (float)hh);
    }
}

__global__ __launch_bounds__(256) void split_f32(const float* __restrict__ in,
                                                 half_t* __restrict__ hi, half_t* __restrict__ lo)
{
    long i = ((long)blockIdx.x * 256 + threadIdx.x) * 8;
    float4 a = *(const float4*)(in + i), b = *(const float4*)(in + i + 4);
    float v[8] = {a.x, a.y, a.z, a.w, b.x, b.y, b.z, b.w};
    half8 hv, lv;
#pragma unroll
    for (int j = 0; j < 8; ++j) {
        half_t hh = (half_t)v[j];
        hv[j] = hh;
        lv[j] = (half_t)(v[j] - (float)hh);
    }
    *(half8*)(hi + i) = hv;
    *(half8*)(lo + i) = lv;
}

// ============================================================================
// host-side dispatch
// ============================================================================
static void launch_gemm16(hipStream_t s, int epi,
    const half_t* Ahi, const half_t* Alo, long lda, long sA,
    const half_t* Bhi, const half_t* Blo, long ldb, long sB,
    float* Cf, half_t* Chi, half_t* Clo, long ldc, long sC, long slotS,
    int M, int N, int K, int batch, float alpha,
    const float* bias, const float* tvec, float* rsum)
{
    dim3 g(N / 128, M / 128, batch), b(256, 1, 1);
    if (epi == 0)      gemm_f16s<0><<<g, b, 0, s>>>(Ahi, Alo, lda, sA, Bhi, Blo, ldb, sB, Cf, Chi, Clo, ldc, sC, slotS, K, alpha, bias, tvec, rsum);
    else if (epi == 1) gemm_f16s<1><<<g, b, 0, s>>>(Ahi, Alo, lda, sA, Bhi, Blo, ldb, sB, Cf, Chi, Clo, ldc, sC, slotS, K, alpha, bias, tvec, rsum);
    else if (epi == 3) gemm_f16s<3><<<g, b, 0, s>>>(Ahi, Alo, lda, sA, Bhi, Blo, ldb, sB, Cf, Chi, Clo, ldc, sC, slotS, K, alpha, bias, tvec, rsum);
    else               gemm_f16s<4><<<g, b, 0, s>>>(Ahi, Alo, lda, sA, Bhi, Blo, ldb, sB, Cf, Chi, Clo, ldc, sC, slotS, K, alpha, bias, tvec, rsum);
}

static void launch_g256(hipStream_t s, int mf, int epi,
    const half_t* Ahi, const half_t* Alo, long lda, long sA,
    const half_t* Bhi, const half_t* Blo, long ldb, long sB,
    float* Cf, half_t* Chi, half_t* Clo, long ldc, long sC, long slotS,
    int M, int N, int K, int batch, float alpha,
    const float* tvec, float* rsum)
{
    dim3 b(512, 1, 1);
    if (mf == 8) {
        dim3 g(N / 256, M / 256, batch);
        const size_t sh = 131072;   // 2 * PERBUF(MF=8) * 2B
        if (epi == 0)      gemm256<8, 0><<<g, b, sh, s>>>(Ahi, Alo, lda, sA, Bhi, Blo, ldb, sB, Cf, Chi, Clo, ldc, sC, slotS, K, alpha, tvec, rsum);
        else if (epi == 1) gemm256<8, 1><<<g, b, sh, s>>>(Ahi, Alo, lda, sA, Bhi, Blo, ldb, sB, Cf, Chi, Clo, ldc, sC, slotS, K, alpha, tvec, rsum);
        else               gemm256<8, 3><<<g, b, sh, s>>>(Ahi, Alo, lda, sA, Bhi, Blo, ldb, sB, Cf, Chi, Clo, ldc, sC, slotS, K, alpha, tvec, rsum);
    } else {
        dim3 g(N / 256, M / 128, batch);
        const size_t sh = 98304;    // 2 * PERBUF(MF=4) * 2B
        gemm256<4, 1><<<g, b, sh, s>>>(Ahi, Alo, lda, sA, Bhi, Blo, ldb, sB, Cf, Chi, Clo, ldc, sC, slotS, K, alpha, tvec, rsum);
    }
}

extern "C" void kernel_launch(void* const* d_in, const int* in_sizes, int n_in,
                              void* d_out, int out_size, void* d_ws, size_t ws_size,
                              hipStream_t stream)
{
    const float* X   = (const float*)d_in[0];
    const float* Wq1 = (const float*)d_in[1];
    const float* Wk1 = (const float*)d_in[2];
    const float* Wv1 = (const float*)d_in[3];
    const float* Wo1 = (const float*)d_in[4];
    const float* Wq2 = (const float*)d_in[5];
    const float* Wk2 = (const float*)d_in[6];
    const float* W1  = (const float*)d_in[7];
    const float* b1  = (const float*)d_in[8];
    const float* W2  = (const float*)d_in[9];
    const float* b2  = (const float*)d_in[10];

    float* out = (float*)d_out;
    const float scale = 0.044194173824159216f;
    const float WM = 8.0f, WMI = 0.125f;

    // static device property -> identical decision every call (capture-safe)
    int dev = 0;
    hipGetDevice(&dev);
    int maxSh = 0;
    hipDeviceGetAttribute(&maxSh, hipDeviceAttributeMaxSharedMemoryPerBlock, dev);
    const bool big = (maxSh >= 131072);

    // ---- workspace layout ----
    half_t* wsH = (half_t*)d_ws;
    const long U  = (long)MT * DD;
    const long WD = (long)DD * DD;
    half_t* sXh = wsH;          half_t* sXl = wsH + U;
    half_t* sBh = wsH + 2 * U;  half_t* sBl = wsH + 3 * U;
    half_t* sCh = wsH + 4 * U;  half_t* sCl = wsH + 5 * U;
    half_t* wptr = wsH + 6 * U;
    half_t* mb1h = wptr;            half_t* mb1l = mb1h + WD;
    half_t* mvoh = mb1l + WD;       half_t* mvol = mvoh + WD;
    half_t* mb2h = mvol + WD;       half_t* mb2l = mb2h + WD;
    half_t* w1h  = mb2l + WD;       half_t* w1l  = w1h + (long)DD * CFF;
    float*  T0 = (float*)(w1l + (long)DD * CFF);
    float*  T1 = T0 + WD;
    float*  T2 = T1 + WD;
    float*  thresh = T2 + WD;
    float*  sums   = thresh + MT;

    // ---- prep (shared by both paths) ----
    init_aux<<<dim3(64), dim3(256), 0, stream>>>(thresh, sums, b2);
    split_f32<<<dim3(4096), dim3(256), 0, stream>>>(X, sXh, sXl);
    wgemm3<<<dim3(8, 8, 3), dim3(256), 0, stream>>>(Wq1, Wk1, Wv1, Wo1, Wq2, Wk2, T0, T1, T2);
    wprep<<<dim3(16, 16), dim3(256), 0, stream>>>(T0, mb1h, mb1l, DD, DD, WM);
    wprep<<<dim3(16, 16), dim3(256), 0, stream>>>(T1, mvoh, mvol, DD, DD, WM);
    wprep<<<dim3(16, 16), dim3(256), 0, stream>>>(T2, mb2h, mb2l, DD, DD, WM);
    wprep<<<dim3(4, 16),  dim3(256), 0, stream>>>(W1, w1h, w1l, DD, CFF, 1.0f);

    const half_t* p1h = (const half_t*)d_out;
    const half_t* p1l = p1h + NN;

    if (big) {
        // 1) y1 = X @ (Wq1 Wk1^T) -> slot B
        launch_g256(stream, 8, 1, sXh, sXl, DD, 0, mb1h, mb1l, DD, 0,
                    nullptr, sBh, sBl, DD, 0, 0, MT, DD, DD, 1, WMI, nullptr, nullptr);
        // 2) s1 = scale * y1 @ X^T (batched) -> d_out f32
        launch_g256(stream, 8, 0, sBh, sBl, DD, (long)NN * DD, sXh, sXl, DD, (long)NN * DD,
                    out, nullptr, nullptr, NN, (long)NN * NN, 0, NN, NN, DD, BB, scale, nullptr, nullptr);
        // 3) voT = (Wv1 Wo1)^T @ X^T (batched) -> slot B [8][512][2048]
        launch_g256(stream, 8, 1, mvoh, mvol, DD, 0, sXh, sXl, DD, (long)NN * DD,
                    nullptr, sBh, sBl, NN, (long)DD * NN, 512, DD, NN, DD, BB, WMI, nullptr, nullptr);
        // 4) softmax(s1) -> p1 hi/lo f16 in place
        softmax_split_kernel<<<dim3(MT), dim3(256), 0, stream>>>(out);
        // 5) att = p1 @ vo (batched, BM=128 variant) -> slot C
        launch_g256(stream, 4, 1, p1h, p1l, 2 * NN, (long)NN * 2 * NN,
                    sBh, sBl, NN, (long)DD * NN,
                    nullptr, sCh, sCl, DD, (long)NN * DD, 0, NN, DD, NN, BB, 1.f, nullptr, nullptr);
        // 6) y2 = att @ (Wq2 Wk2^T) -> slot B
        launch_g256(stream, 8, 1, sCh, sCl, DD, 0, mb2h, mb2l, DD, 0,
                    nullptr, sBh, sBl, DD, 0, 0, MT, DD, DD, 1, WMI, nullptr, nullptr);
        // 7) fused h+thresh
        {
            dim3 g(CFF / 128, MT / 128), b(256, 1, 1);
            gemm_h<<<g, b, 0, stream>>>(sCh, sCl, DD, w1h, w1l, DD, DD, b1, W2, thresh);
        }
        // 8) surv = max(scale * y2 @ att^T - thresh, 0) -> d_out + row sums
        launch_g256(stream, 8, 3, sBh, sBl, DD, (long)NN * DD, sCh, sCl, DD, (long)NN * DD,
                    out, nullptr, nullptr, NN, (long)NN * NN, 0, NN, NN, DD, BB, scale, thresh, sums);
    } else {
        // ---- fallback: full r5 pipeline (proven) ----
        launch_gemm16(stream, 1, sXh, sXl, DD, 0, mb1h, mb1l, DD, 0,
                      nullptr, sBh, sBl, DD, 0, 0, MT, DD, DD, 1, WMI, nullptr, nullptr, nullptr);
        launch_gemm16(stream, 0, sBh, sBl, DD, (long)NN * DD, sXh, sXl, DD, (long)NN * DD,
                      out, nullptr, nullptr, NN, (long)NN * NN, 0, NN, NN, DD, BB, scale, nullptr, nullptr, nullptr);
        launch_gemm16(stream, 1, mvoh, mvol, DD, 0, sXh, sXl, DD, (long)NN * DD,
                      nullptr, sBh, sBl, NN, (long)DD * NN, 512, DD, NN, DD, BB, WMI, nullptr, nullptr, nullptr);
        softmax_split_kernel<<<dim3(MT), dim3(256), 0, stream>>>(out);
        launch_gemm16(stream, 1, p1h, p1l, 2 * NN, (long)NN * 2 * NN,
                      sBh, sBl, NN, (long)DD * NN,
                      nullptr, sCh, sCl, DD, (long)NN * DD, 0, NN, DD, NN, BB, 1.f, nullptr, nullptr, nullptr);
        launch_gemm16(stream, 1, sCh, sCl, DD, 0, mb2h, mb2l, DD, 0,
                      nullptr, sBh, sBl, DD, 0, 0, MT, DD, DD, 1, WMI, nullptr, nullptr, nullptr);
        launch_gemm16(stream, 4, sCh, sCl, DD, 0, w1h, w1l, DD, 0,
                      nullptr, nullptr, nullptr, CFF, 0, 0, MT, CFF, DD, 1, 1.f, b1, W2, thresh);
        launch_gemm16(stream, 3, sBh, sBl, DD, (long)NN * DD, sCh, sCl, DD, (long)NN * DD,
                      out, nullptr, nullptr, NN, (long)NN * NN, 0, NN, NN, DD, BB, scale, nullptr, thresh, sums);
    }

    // 9) A = clip(surv/(sum+1e-9), 0, 1)
    norm_kernel<<<dim3(out_size / 2048), dim3(256), 0, stream>>>(out, sums);
}